// Round 4
// baseline (257.217 us; speedup 1.0000x reference)
//
#include <hip/hip_runtime.h>
#include <math.h>

// EMA (adjust=True, alpha=2/26) over x[32][4096][256] f32.
// e_t = (alpha*x_t + oma*e_{t-1}) / w_t, w_t = max(1-oma^(t+1), 1e-10).
//
// R4 design: latency-bound fix. 64 chunks of 64 rows per batch (2048 blocks,
// 8 waves/CU) with a 128-row warm-up halo (damping oma^128 ~ 3.5e-5, below
// threshold). Chunks with any t < 256 (c < 6) compute exact per-t w via a
// double-precision running power; chunks c >= 6 have w_t == 1.0f exactly
// (t >= 216) -> bare fma. XCD-swizzled blockIdx so neighboring chunks of one
// batch share an XCD L2 (halo re-reads are L2/L3 hits, not HBM).

namespace {

constexpr int kT = 4096;
constexpr int kF4 = 64;        // 256 floats / float4
constexpr int kL = 64;         // chunk length (rows)
constexpr int kHalo = 128;     // warm-up rows (chunks >= 2)
constexpr int kNC = kT / kL;   // 64 chunks per batch
constexpr int kG = 16;         // rows per pipelined group
constexpr int kBatches = 32;
constexpr int kBlocks = kBatches * kNC;  // 2048

constexpr double kAlphaD = 2.0 / 26.0;
constexpr float kAlpha = (float)kAlphaD;          // jnp.asarray(ALPHA, f32)
constexpr float kOma   = (float)(1.0 - kAlphaD);  // jnp.asarray(1-ALPHA, f32)

__device__ __forceinline__ void load_group(const float4* __restrict__ p,
                                           float4 (&buf)[kG]) {
#pragma unroll
  for (int i = 0; i < kG; ++i) buf[i] = p[i * kF4];
}

__device__ __forceinline__ void store_group(float4* __restrict__ p,
                                            const float4 (&buf)[kG]) {
#pragma unroll
  for (int i = 0; i < kG; ++i) p[i * kF4] = buf[i];
}

__device__ __forceinline__ void step_fast(float4& e, const float4 v) {
  e.x = fmaf(kOma, e.x, kAlpha * v.x);
  e.y = fmaf(kOma, e.y, kAlpha * v.y);
  e.z = fmaf(kOma, e.z, kAlpha * v.z);
  e.w = fmaf(kOma, e.w, kAlpha * v.w);
}

template <bool EXACT>
__device__ __forceinline__ void process_group(float4 (&buf)[kG], float4& e,
                                              double& p, int tbase) {
#pragma unroll
  for (int i = 0; i < kG; ++i) {
    const float4 v = buf[i];
    if (EXACT) {
      if (tbase + i == 0) {
        e = v;  // e0 = x[:,0,:]
      } else {
        p *= (double)kOma;  // p = oma^(t+1)
        const float w = fmaxf(1.0f - (float)p, 1e-10f);
        const float inv = 1.0f / w;
        step_fast(e, v);
        e.x *= inv; e.y *= inv; e.z *= inv; e.w *= inv;
      }
    } else {
      step_fast(e, v);
    }
    buf[i] = e;
  }
}

// ng groups total (even), last (ng-hg) groups stored. px at halo start,
// po at chunk output start.
template <bool EXACT>
__device__ __forceinline__ void run_chunk(const float4* __restrict__ px,
                                          float4* __restrict__ po,
                                          int ng, int hg, int t0) {
  float4 e = make_float4(0.f, 0.f, 0.f, 0.f);
  float4 bufA[kG], bufB[kG];
  double p = 0.0;
  if (EXACT) {
    // p = oma^(t0+1); exact-path steps multiply before use -> init to oma^t0.
    p = pow((double)kOma, (double)t0);
    if (t0 == 0) p = 1.0;  // so first multiplied value is oma^1... (t=0 special-cased anyway)
  }
  // Keep p semantics identical to R3: after handling row t (t>=1), p == oma^(t+1).
  // Init so that the first "p *= oma" yields oma^(t_first+1):
  if (EXACT) p = pow((double)kOma, (double)(t0 == 0 ? 1 : t0));
  // (for t0==0 the t==0 row is special-cased and does not touch p; the t==1 row
  //  then computes p = oma^1 * oma = oma^2 ✓. For t0>0 the first row computes
  //  p = oma^t0 * oma = oma^(t0+1) ✓.)

  load_group(px, bufA);
  px += kG * kF4;
  for (int g = 0; g < ng; g += 2) {
    load_group(px, bufB);  // ng even -> g+1 < ng always inside the loop
    px += kG * kF4;
    process_group<EXACT>(bufA, e, p, t0 + g * kG);
    if (g >= hg) {
      store_group(po, bufA);
      po += kG * kF4;
    }
    if (g + 2 < ng) {
      load_group(px, bufA);
      px += kG * kF4;
    }
    process_group<EXACT>(bufB, e, p, t0 + (g + 1) * kG);
    if (g + 1 >= hg) {
      store_group(po, bufB);
      po += kG * kF4;
    }
  }
}

}  // namespace

__global__ __launch_bounds__(64, 2) void ema_kernel(const float* __restrict__ x,
                                                    float* __restrict__ out) {
  // Bijective XCD swizzle (2048 % 8 == 0): each XCD gets a contiguous run of
  // 256 (b,c) pairs -> a batch's neighboring chunks share an XCD L2.
  const int sw = (blockIdx.x & 7) * (kBlocks / 8) + (blockIdx.x >> 3);
  const int b = sw / kNC;     // batch
  const int c = sw & (kNC - 1);  // chunk within batch

  const int t0 = (c >= 2) ? (c * kL - kHalo) : 0;   // halo start row
  const int rows = (c == 0) ? kL : (c == 1 ? 2 * kL : kHalo + kL);
  const int ng = rows / kG;                          // 4, 8, or 12 (even)
  const int hg = (c * kL - t0) / kG;                 // halo groups: 0, 4, or 8

  const float4* px = reinterpret_cast<const float4*>(x) +
                     ((size_t)b * kT + t0) * kF4 + threadIdx.x;
  float4* po = reinterpret_cast<float4*>(out) +
               ((size_t)b * kT + (size_t)c * kL) * kF4 + threadIdx.x;

  if (c < 6) {
    run_chunk<true>(px, po, ng, hg, t0);   // covers every row with t < 256
  } else {
    run_chunk<false>(px, po, ng, hg, t0);  // all rows t >= 256: w == 1.0f exactly
  }
}

extern "C" void kernel_launch(void* const* d_in, const int* in_sizes, int n_in,
                              void* d_out, int out_size, void* d_ws, size_t ws_size,
                              hipStream_t stream) {
  (void)in_sizes; (void)n_in; (void)d_ws; (void)ws_size; (void)out_size;
  const float* x = reinterpret_cast<const float*>(d_in[0]);
  float* out = reinterpret_cast<float*>(d_out);
  hipLaunchKernelGGL(ema_kernel, dim3(kBlocks), dim3(64), 0, stream, x, out);
}

// Round 5
// 240.836 us; speedup vs baseline: 1.0680x; 1.0680x over previous
//
#include <hip/hip_runtime.h>

// EMA (adjust=True, alpha=2/26) over x[32][4096][256] f32.
// e_t = (alpha*x_t + oma*e_{t-1}) / w_t, w_t = max(1-oma^(t+1), 1e-10).
//
// R5: demand-traffic fix. kL=256 rows/chunk (16 chunks/batch), 64-row halo
// (read amplification 1.23x vs R4's 3x). The reference's repeated /w_t
// amplifies early history by ~2.4e5 (ref peaks ~1e6 near t~30-50), but that
// bump is entirely inside exact chunk 0; halo-seeded chunks start at t>=192
// where |e|~O(1), so halo error ~ O(1)*oma^64 ~ 6e-3 << threshold.
// Occupancy via 2 waves/block (128 thr, float2/lane) = 4 waves/CU, kG=32
// double-buffered groups (64 KB in flight per CU). Nontemporal stores keep
// output from evicting x in L3. Chunks >=1: w_t == 1.0f (t>=216) -> bare fma.

namespace {

typedef float f2 __attribute__((ext_vector_type(2)));

constexpr int kT = 4096;
constexpr int kF2 = 128;       // float2 elements per row (256 floats)
constexpr int kL = 256;        // chunk length (rows)
constexpr int kHalo = 64;      // warm-up rows for chunks >= 1
constexpr int kNC = kT / kL;   // 16 chunks per batch
constexpr int kG = 32;         // rows per pipelined group
constexpr int kBatches = 32;
constexpr int kBlocks = kBatches * kNC;  // 512

constexpr double kAlphaD = 2.0 / 26.0;
constexpr float kAlpha = (float)kAlphaD;          // jnp.asarray(ALPHA, f32)
constexpr float kOma   = (float)(1.0 - kAlphaD);  // jnp.asarray(1-ALPHA, f32)

__device__ __forceinline__ void load_group(const f2* __restrict__ p,
                                           f2 (&buf)[kG]) {
#pragma unroll
  for (int i = 0; i < kG; ++i) buf[i] = p[(size_t)i * kF2];
}

__device__ __forceinline__ void store_group(f2* __restrict__ p,
                                            const f2 (&buf)[kG]) {
#pragma unroll
  for (int i = 0; i < kG; ++i)
    __builtin_nontemporal_store(buf[i], p + (size_t)i * kF2);
}

__device__ __forceinline__ void step_fast(f2& e, const f2 v) {
  e.x = fmaf(kOma, e.x, kAlpha * v.x);
  e.y = fmaf(kOma, e.y, kAlpha * v.y);
}

template <bool EXACT>
__device__ __forceinline__ void process_group(f2 (&buf)[kG], f2& e,
                                              double& p, int tbase) {
#pragma unroll
  for (int i = 0; i < kG; ++i) {
    const f2 v = buf[i];
    if (EXACT) {
      if (tbase + i == 0) {
        e = v;  // e0 = x[:,0,:]
      } else {
        p *= (double)kOma;  // p = oma^(t+1)
        const float w = fmaxf(1.0f - (float)p, 1e-10f);
        const float inv = 1.0f / w;
        step_fast(e, v);
        e.x *= inv; e.y *= inv;
      }
    } else {
      step_fast(e, v);  // w == 1.0f exactly for t >= 216
    }
    buf[i] = e;
  }
}

// ng groups total (even); last (ng-hg) groups stored. px at halo start,
// po at chunk output start. EXACT only used with t0 == 0.
template <bool EXACT>
__device__ __forceinline__ void run_chunk(const f2* __restrict__ px,
                                          f2* __restrict__ po,
                                          int ng, int hg, int t0) {
  f2 e = {0.f, 0.f};
  f2 bufA[kG], bufB[kG];
  // After handling row t (t>=1), p == oma^(t+1). Row 0 is special-cased, so
  // init p = oma^1: the t=1 step computes p = oma^2 = oma^(t+1).
  double p = (double)kOma;

  load_group(px, bufA);
  px += (size_t)kG * kF2;
  for (int g = 0; g < ng; g += 2) {
    load_group(px, bufB);  // ng even -> group g+1 always exists
    px += (size_t)kG * kF2;
    process_group<EXACT>(bufA, e, p, t0 + g * kG);
    if (g >= hg) {
      store_group(po, bufA);
      po += (size_t)kG * kF2;
    }
    if (g + 2 < ng) {
      load_group(px, bufA);
      px += (size_t)kG * kF2;
    }
    process_group<EXACT>(bufB, e, p, t0 + (g + 1) * kG);
    if (g + 1 >= hg) {
      store_group(po, bufB);
      po += (size_t)kG * kF2;
    }
  }
}

}  // namespace

__global__ __launch_bounds__(128) void ema_kernel(const float* __restrict__ x,
                                                  float* __restrict__ out) {
  // Bijective XCD swizzle (512 % 8 == 0): each XCD gets 64 consecutive (b,c)
  // pairs = 4 whole batches -> chunk-halo overlap stays in one XCD's L2.
  const int sw = (blockIdx.x & 7) * (kBlocks / 8) + (blockIdx.x >> 3);
  const int b = sw / kNC;
  const int c = sw & (kNC - 1);
  const int tid = threadIdx.x;  // 0..127, owns 2 consecutive floats

  if (c == 0) {
    // Exact prefix t = 0..255 (covers every row with w < 1 and the ~1e6 bump).
    const f2* px = reinterpret_cast<const f2*>(x) + (size_t)b * kT * kF2 + tid;
    f2* po = reinterpret_cast<f2*>(out) + (size_t)b * kT * kF2 + tid;
    run_chunk<true>(px, po, kL / kG /*8*/, 0, 0);
  } else {
    // 64-row warm-up halo + 256-row body, all bare fma (w == 1.0f).
    const int t0 = c * kL - kHalo;
    const f2* px = reinterpret_cast<const f2*>(x) +
                   ((size_t)b * kT + t0) * kF2 + tid;
    f2* po = reinterpret_cast<f2*>(out) +
             ((size_t)b * kT + (size_t)c * kL) * kF2 + tid;
    run_chunk<false>(px, po, (kL + kHalo) / kG /*10*/, kHalo / kG /*2*/, t0);
  }
}

extern "C" void kernel_launch(void* const* d_in, const int* in_sizes, int n_in,
                              void* d_out, int out_size, void* d_ws, size_t ws_size,
                              hipStream_t stream) {
  (void)in_sizes; (void)n_in; (void)d_ws; (void)ws_size; (void)out_size;
  const float* x = reinterpret_cast<const float*>(d_in[0]);
  float* out = reinterpret_cast<float*>(d_out);
  hipLaunchKernelGGL(ema_kernel, dim3(kBlocks), dim3(128), 0, stream, x, out);
}

// Round 11
// 238.530 us; speedup vs baseline: 1.0783x; 1.0097x over previous
//
#include <hip/hip_runtime.h>

// EMA (adjust=True, alpha=2/26) over x[32][4096][256] f32.
// e_t = (alpha*x_t + oma*e_{t-1}) / w_t, w_t = max(1-oma^(t+1), 1e-10).
//
// R6: R3's proven wave microstructure (float4 lanes, 64-thread blocks,
// launch_bounds(64,1), plain stores, compile-time loop bounds) + 2x grid:
// kL=256 (16 chunks/batch, 512 blocks = 2 waves/CU), 64-row halo.
// Halo error: seed O(1) * oma^64 ~ 6e-3 (measured 0.038 in R5) << 1.9e4
// threshold. The ~1e6 early-t bump (repeated /w amplification) lives in
// t<200, entirely inside exact chunk 0. For halo rows t>=192 w deviates
// from 1.0f by <=2e-7 (negligible, absorbed in warm-up); body rows t>=256
// have w == 1.0f exactly -> bare fma matches reference arithmetic.

namespace {

constexpr int kT = 4096;
constexpr int kF4 = 64;        // float4 per row (256 floats)
constexpr int kL = 256;        // chunk length (rows)
constexpr int kHalo = 64;      // warm-up rows for chunks >= 1
constexpr int kNC = kT / kL;   // 16 chunks per batch
constexpr int kG = 16;         // rows per pipelined group
constexpr int kBatches = 32;
constexpr int kBlocks = kBatches * kNC;  // 512

constexpr double kAlphaD = 2.0 / 26.0;
constexpr float kAlpha = (float)kAlphaD;          // jnp.asarray(ALPHA, f32)
constexpr float kOma   = (float)(1.0 - kAlphaD);  // jnp.asarray(1-ALPHA, f32)

__device__ __forceinline__ void load_group(const float4* __restrict__ p,
                                           float4 (&buf)[kG]) {
#pragma unroll
  for (int i = 0; i < kG; ++i) buf[i] = p[i * kF4];
}

__device__ __forceinline__ void store_group(float4* __restrict__ p,
                                            const float4 (&buf)[kG]) {
#pragma unroll
  for (int i = 0; i < kG; ++i) p[i * kF4] = buf[i];
}

__device__ __forceinline__ void step_fast(float4& e, const float4 v) {
  e.x = fmaf(kOma, e.x, kAlpha * v.x);
  e.y = fmaf(kOma, e.y, kAlpha * v.y);
  e.z = fmaf(kOma, e.z, kAlpha * v.z);
  e.w = fmaf(kOma, e.w, kAlpha * v.w);
}

template <bool EXACT>
__device__ __forceinline__ void process_group(float4 (&buf)[kG], float4& e,
                                              double& p, int tbase) {
#pragma unroll
  for (int i = 0; i < kG; ++i) {
    const float4 v = buf[i];
    if (EXACT) {
      if (tbase + i == 0) {
        e = v;  // e0 = x[:,0,:]
      } else {
        p *= (double)kOma;  // p = oma^(t+1)  (verified exact in R3, absmax 0.0)
        const float w = fmaxf(1.0f - (float)p, 1e-10f);
        const float inv = 1.0f / w;
        step_fast(e, v);
        e.x *= inv; e.y *= inv; e.z *= inv; e.w *= inv;
      }
    } else {
      step_fast(e, v);  // w == 1.0f for all fast-path rows
    }
    buf[i] = e;
  }
}

// NG groups total (even); groups >= HG stored. All bounds compile-time.
template <bool EXACT, int NG, int HG>
__device__ __forceinline__ void run_chunk(const float4* __restrict__ px,
                                          float4* __restrict__ po, int t0) {
  float4 e = make_float4(0.f, 0.f, 0.f, 0.f);
  float4 bufA[kG], bufB[kG];
  // After handling row t (t>=1), p == oma^(t+1). Row 0 special-cased, so the
  // first multiply (t=1) must yield oma^2 -> init p = oma^1.
  double p = (double)kOma;

  load_group(px, bufA);
  px += kG * kF4;
  for (int g = 0; g < NG; g += 2) {
    load_group(px, bufB);  // NG even -> group g+1 always exists
    px += kG * kF4;
    process_group<EXACT>(bufA, e, p, t0 + g * kG);
    if (g >= HG) {
      store_group(po, bufA);
      po += kG * kF4;
    }
    if (g + 2 < NG) {
      load_group(px, bufA);
      px += kG * kF4;
    }
    process_group<EXACT>(bufB, e, p, t0 + (g + 1) * kG);
    if (g + 1 >= HG) {
      store_group(po, bufB);
      po += kG * kF4;
    }
  }
}

}  // namespace

__global__ __launch_bounds__(64, 1) void ema_kernel(const float* __restrict__ x,
                                                    float* __restrict__ out) {
  const int blk = blockIdx.x;
  const int c = blk & (kNC - 1);   // chunk within batch
  const int b = blk / kNC;         // batch
  const int lane = threadIdx.x;    // 0..63, owns 4 consecutive floats

  if (c == 0) {
    // Exact prefix t = 0..255 with per-t w (covers all w<1 rows + the bump).
    const float4* px = reinterpret_cast<const float4*>(x) +
                       (size_t)b * kT * kF4 + lane;
    float4* po = reinterpret_cast<float4*>(out) + (size_t)b * kT * kF4 + lane;
    run_chunk<true, kL / kG /*16*/, 0>(px, po, 0);
  } else {
    // 64-row warm-up halo + 256-row body, bare fma.
    const int t0 = c * kL - kHalo;
    const float4* px = reinterpret_cast<const float4*>(x) +
                       ((size_t)b * kT + t0) * kF4 + lane;
    float4* po = reinterpret_cast<float4*>(out) +
                 ((size_t)b * kT + (size_t)c * kL) * kF4 + lane;
    run_chunk<false, (kL + kHalo) / kG /*20*/, kHalo / kG /*4*/>(px, po, t0);
  }
}

extern "C" void kernel_launch(void* const* d_in, const int* in_sizes, int n_in,
                              void* d_out, int out_size, void* d_ws, size_t ws_size,
                              hipStream_t stream) {
  (void)in_sizes; (void)n_in; (void)d_ws; (void)ws_size; (void)out_size;
  const float* x = reinterpret_cast<const float*>(d_in[0]);
  float* out = reinterpret_cast<float*>(d_out);
  hipLaunchKernelGGL(ema_kernel, dim3(kBlocks), dim3(64), 0, stream, x, out);
}